// Round 3
// baseline (418.907 us; speedup 1.0000x reference)
//
#include <hip/hip_runtime.h>
#include <hip/hip_bf16.h>

// Problem: out[n] = sigmoid( u[n] . W[type_idx[n]] . v[n] ),  N=131072, D=256, K=8
// v2: group-by-type -> grouped skinny GEMM (fp16 MFMA).
//     - NO LDS, NO in-loop barriers in main (W is L2-resident; LDS staging was
//       pure overhead and its barriers blocked V-load pipelining -> latency-bound).
//     - B-fragments read directly from Wt (L2), ec-loop fully unrolled so the
//       compiler hoists V/B loads across iterations.
//     - convw+hist fused into one prep kernel.

#define N_SAMPLES 131072
#define DIM 256
#define KTYPES 8
#define TILE_M 64                      // rows per workgroup (4 waves x 16)
#define MAXTILES (N_SAMPLES / TILE_M + KTYPES)   // 2048 + 8 = 2056

typedef _Float16 f16x8 __attribute__((ext_vector_type(8)));
typedef float f32x4 __attribute__((ext_vector_type(4)));

// ---------------- ws layout ----------------
#define WT_OFF   ((size_t)0)            // 1MB: Wt fp16 [k][e][d]
#define CNT_OFF  ((size_t)0x100000)     // counts[8] (zeroed)
#define CUR_OFF  ((size_t)0x100020)     // cursors[8] (zeroed)
#define GOF_OFF  ((size_t)0x100040)     // goff[8]
#define DESC_OFF ((size_t)0x100080)     // desc[MAXTILES] int4
#define PERM_OFF (DESC_OFF + (size_t)MAXTILES * 16)   // perm[N] int

// Pass A (fused): W fp32 [k][d][e] -> Wt fp16 [k][e][d], plus histogram of idx.
__global__ void prep_kernel(const float* __restrict__ W, _Float16* __restrict__ Wt,
                            const int* __restrict__ idx, int* __restrict__ counts) {
    __shared__ int lcnt[KTYPES];
    if (threadIdx.x < KTYPES) lcnt[threadIdx.x] = 0;
    __syncthreads();

    int g = blockIdx.x * 256 + threadIdx.x;    // 131072 threads
    // --- W convert/transpose ---
    {
        int d  = g & 255;
        int e0 = ((g >> 8) & 63) * 4;
        int k  = g >> 14;
        const float* src = W + ((size_t)k << 16) + (size_t)d * 256 + e0;
        float4 vv = *(const float4*)src;
        _Float16* dst = Wt + ((size_t)k << 16) + d;
        dst[(size_t)(e0 + 0) * 256] = (_Float16)vv.x;
        dst[(size_t)(e0 + 1) * 256] = (_Float16)vv.y;
        dst[(size_t)(e0 + 2) * 256] = (_Float16)vv.z;
        dst[(size_t)(e0 + 3) * 256] = (_Float16)vv.w;
    }
    // --- histogram ---
    atomicAdd(&lcnt[idx[g]], 1);
    __syncthreads();
    if (threadIdx.x < KTYPES && lcnt[threadIdx.x] > 0)
        atomicAdd(&counts[threadIdx.x], lcnt[threadIdx.x]);
}

// Pass B: prefix offsets + tile descriptors (single block)
__global__ void plan_kernel(const int* __restrict__ counts, int* __restrict__ goff,
                            int4* __restrict__ desc) {
    __shared__ int s_goff[KTYPES + 1], s_tstart[KTYPES + 1], s_cnt[KTYPES];
    if (threadIdx.x == 0) {
        int off = 0, toff = 0;
        for (int k = 0; k < KTYPES; ++k) {
            int c = counts[k];
            s_cnt[k] = c;
            s_goff[k] = off; s_tstart[k] = toff;
            goff[k] = off;
            off += c;
            toff += (c + TILE_M - 1) / TILE_M;
        }
        s_goff[KTYPES] = off; s_tstart[KTYPES] = toff;
    }
    __syncthreads();
    int total = s_tstart[KTYPES];
    for (int t = threadIdx.x; t < MAXTILES; t += blockDim.x) {
        int4 dd;
        if (t < total) {
            int k = 0;
            while (t >= s_tstart[k + 1]) ++k;
            dd.x = k;
            dd.y = (t - s_tstart[k]) * TILE_M;
            dd.z = s_goff[k];
            dd.w = s_cnt[k];
        } else {
            dd = make_int4(-1, 0, 0, 0);
        }
        desc[t] = dd;
    }
}

// Pass C: scatter sample ids into per-type contiguous regions of perm
__global__ void scatter_kernel(const int* __restrict__ idx, const int* __restrict__ goff,
                               int* __restrict__ cursors, int* __restrict__ perm) {
    __shared__ int lcnt[KTYPES], lbase[KTYPES];
    int tid = threadIdx.x;
    if (tid < KTYPES) lcnt[tid] = 0;
    __syncthreads();
    int n = blockIdx.x * 256 + tid;
    int k = idx[n];
    int lpos = atomicAdd(&lcnt[k], 1);
    __syncthreads();
    if (tid < KTYPES)
        lbase[tid] = (lcnt[tid] > 0) ? atomicAdd(&cursors[tid], lcnt[tid]) : 0;
    __syncthreads();
    perm[goff[k] + lbase[k] + lpos] = n;
}

// Pass D: grouped GEMM tile. 4 waves x 16 rows. NO LDS, NO barriers:
// B-fragments straight from Wt (L2-resident, 1MB), ec-loop fully unrolled so
// V loads pipeline across iterations.
// MFMA fragment maps (gfx950 16x16x32):
//   A[m][kk]: m = lane&15, kk = (lane>>4)*8 + j
//   B[kk][n]: n = lane&15, kk = (lane>>4)*8 + j
//   D[m][n] : n = lane&15, m = (lane>>4)*4 + r
__global__ __launch_bounds__(256, 4) void bilinear_main(
    const float* __restrict__ U, const float* __restrict__ V,
    const _Float16* __restrict__ Wt, const int* __restrict__ perm,
    const int4* __restrict__ desc, float* __restrict__ out)
{
    int4 dsc = desc[blockIdx.x];
    int k = dsc.x;
    if (k < 0) return;
    int local_base = dsc.y, goff = dsc.z, count = dsc.w;

    int tid  = threadIdx.x;
    int wave = tid >> 6, lane = tid & 63;
    int lq = lane >> 4, lm = lane & 15;

    const _Float16* Wk = Wt + ((size_t)k << 16);

    // ---- A fragments: row = wave*16 + lm, kept in registers
    int arow_local = wave * 16 + lm;
    bool avalid = (local_base + arow_local) < count;
    int an = perm[goff + local_base + (avalid ? arow_local : 0)];
    f16x8 afrag[8];
    {
        const float* up = U + ((size_t)an << 8) + lq * 8;
        #pragma unroll
        for (int ks = 0; ks < 8; ++ks) {
            float4 f0 = *(const float4*)(up + ks * 32);
            float4 f1 = *(const float4*)(up + ks * 32 + 4);
            f16x8 a;
            a[0] = (_Float16)f0.x; a[1] = (_Float16)f0.y;
            a[2] = (_Float16)f0.z; a[3] = (_Float16)f0.w;
            a[4] = (_Float16)f1.x; a[5] = (_Float16)f1.y;
            a[6] = (_Float16)f1.z; a[7] = (_Float16)f1.w;
            afrag[ks] = a;
        }
    }

    // ---- rows this lane accumulates in C/D: row = wave*16 + lq*4 + r
    int vrow[4]; bool vvalid[4];
    #pragma unroll
    for (int r = 0; r < 4; ++r) {
        int rl = wave * 16 + lq * 4 + r;
        vvalid[r] = (local_base + rl) < count;
        vrow[r] = perm[goff + local_base + (vvalid[r] ? rl : 0)];
    }

    float spart[4] = {0.f, 0.f, 0.f, 0.f};

    #pragma unroll
    for (int ec = 0; ec < 8; ++ec) {
        // V prefetch for this ec — issued before the MFMA chain; no barriers, so
        // the compiler can hoist these across unrolled iterations.
        float va0[4], va1[4];
        #pragma unroll
        for (int r = 0; r < 4; ++r) {
            const float* vp = V + ((size_t)vrow[r] << 8) + ec * 32;
            va0[r] = vp[lm];
            va1[r] = vp[16 + lm];
        }

        f32x4 acc0 = {0.f, 0.f, 0.f, 0.f};
        f32x4 acc1 = {0.f, 0.f, 0.f, 0.f};
        const _Float16* be0 = Wk + (size_t)((ec * 32 + lm) << 8) + lq * 8;
        #pragma unroll
        for (int ks = 0; ks < 8; ++ks) {
            f16x8 b0 = *(const f16x8*)(be0 + ks * 32);
            f16x8 b1 = *(const f16x8*)(be0 + 16 * 256 + ks * 32);
            acc0 = __builtin_amdgcn_mfma_f32_16x16x32_f16(afrag[ks], b0, acc0, 0, 0, 0);
            acc1 = __builtin_amdgcn_mfma_f32_16x16x32_f16(afrag[ks], b1, acc1, 0, 0, 0);
        }
        #pragma unroll
        for (int r = 0; r < 4; ++r)
            spart[r] += acc0[r] * va0[r] + acc1[r] * va1[r];
    }

    // reduce over the 16 e-lanes (lm); lq preserved by masks 1,2,4,8
    #pragma unroll
    for (int r = 0; r < 4; ++r) {
        float s = spart[r];
        s += __shfl_xor(s, 1);
        s += __shfl_xor(s, 2);
        s += __shfl_xor(s, 4);
        s += __shfl_xor(s, 8);
        spart[r] = s;
    }
    if (lm < 4 && vvalid[lm]) {
        float s = spart[lm];
        out[vrow[lm]] = 1.0f / (1.0f + __expf(-s));
    }
}

extern "C" void kernel_launch(void* const* d_in, const int* in_sizes, int n_in,
                              void* d_out, int out_size, void* d_ws, size_t ws_size,
                              hipStream_t stream) {
    const float* U = (const float*)d_in[0];
    const float* V = (const float*)d_in[1];
    const float* W = (const float*)d_in[2];
    const int* idx = (const int*)d_in[3];
    float* out = (float*)d_out;
    char* ws = (char*)d_ws;

    _Float16* Wt  = (_Float16*)(ws + WT_OFF);
    int* counts   = (int*)(ws + CNT_OFF);
    int* cursors  = (int*)(ws + CUR_OFF);
    int* goff     = (int*)(ws + GOF_OFF);
    int4* desc    = (int4*)(ws + DESC_OFF);
    int* perm     = (int*)(ws + PERM_OFF);

    hipMemsetAsync(ws + CNT_OFF, 0, 64, stream);                  // counts + cursors
    prep_kernel<<<512, 256, 0, stream>>>(W, Wt, idx, counts);
    plan_kernel<<<1, 256, 0, stream>>>(counts, goff, desc);
    scatter_kernel<<<512, 256, 0, stream>>>(idx, goff, cursors, perm);
    bilinear_main<<<MAXTILES, 256, 0, stream>>>(U, V, Wt, perm, desc, out);
}

// Round 4
// 378.466 us; speedup vs baseline: 1.1069x; 1.1069x over previous
//
#include <hip/hip_runtime.h>
#include <hip/hip_bf16.h>

// out[n] = sigmoid( u[n] . W[type_idx[n]] . v[n] ),  N=131072, D=256, K=8
// v3: grouped skinny GEMM, transposed MFMA (T^T = W^T . U^T) so that
//     - acc lanes line up with V rows -> V read as exact fp32 float4 (coalesced)
//     - no barriers / no LDS in main, eb-loop NOT fully unrolled (no spills)
//     - plan kernel removed (blocks derive tiles from counts[8] in-register)

#define N_SAMPLES 131072
#define DIM 256
#define KTYPES 8
#define TILE_M 64
#define MAXTILES (N_SAMPLES / TILE_M + KTYPES)   // 2056

typedef _Float16 f16x8 __attribute__((ext_vector_type(8)));
typedef float f32x4 __attribute__((ext_vector_type(4)));

// ---------------- ws layout ----------------
#define WT_OFF   ((size_t)0)            // 1MB: Wt fp16 [k][e][d]
#define CNT_OFF  ((size_t)0x100000)     // counts[8]  (zeroed)
#define CUR_OFF  ((size_t)0x100020)     // cursors[8] (zeroed)
#define PERM_OFF ((size_t)0x100040)     // perm[N] int

// Pass A: W fp32 [k][d][e] -> Wt fp16 [k][e][d] via LDS 64x64 tile transpose
// (fully coalesced global traffic), fused with idx histogram (int4 loads).
__global__ __launch_bounds__(256) void prep_kernel(
    const float* __restrict__ W, _Float16* __restrict__ Wt,
    const int* __restrict__ idx, int* __restrict__ counts)
{
    __shared__ float lds[64][68];          // pad 68: 16B-aligned rows, spread banks
    __shared__ int lcnt[KTYPES];
    int t = threadIdx.x;
    if (t < KTYPES) lcnt[t] = 0;
    __syncthreads();

    int b = blockIdx.x;                    // 128 blocks
    int k = b >> 4, tile = b & 15;
    int dt = (tile & 3) * 64, et = (tile >> 2) * 64;

    // load 64x64 fp32 tile of W[k]: row r = dt+(t>>2), cols et+(t&3)*16 .. +16
    int r = t >> 2, c0 = (t & 3) * 16;
    const float* src = W + ((size_t)k << 16) + (size_t)(dt + r) * 256 + et + c0;
    float4 x0 = *(const float4*)(src + 0);
    float4 x1 = *(const float4*)(src + 4);
    float4 x2 = *(const float4*)(src + 8);
    float4 x3 = *(const float4*)(src + 12);
    *(float4*)&lds[r][c0 + 0]  = x0;
    *(float4*)&lds[r][c0 + 4]  = x1;
    *(float4*)&lds[r][c0 + 8]  = x2;
    *(float4*)&lds[r][c0 + 12] = x3;

    // histogram: 4 samples per thread
    int4 i4 = ((const int4*)idx)[b * 256 + t];
    atomicAdd(&lcnt[i4.x], 1);
    atomicAdd(&lcnt[i4.y], 1);
    atomicAdd(&lcnt[i4.z], 1);
    atomicAdd(&lcnt[i4.w], 1);
    __syncthreads();

    // write Wt[k][et+e][dt+d0 .. +16): e = t>>2, d0 = (t&3)*16
    int e = t >> 2, d0 = (t & 3) * 16;
    f16x8 o0, o1;
    #pragma unroll
    for (int j = 0; j < 8; ++j) o0[j] = (_Float16)lds[d0 + j][e];
    #pragma unroll
    for (int j = 0; j < 8; ++j) o1[j] = (_Float16)lds[d0 + 8 + j][e];
    _Float16* dst = Wt + ((size_t)k << 16) + (size_t)(et + e) * 256 + dt + d0;
    *(f16x8*)(dst + 0) = o0;
    *(f16x8*)(dst + 8) = o1;

    if (t < KTYPES && lcnt[t] > 0) atomicAdd(&counts[t], lcnt[t]);
}

// Pass B: scatter sample ids into per-type contiguous regions of perm.
// goff derived in-register from counts (no plan kernel).
__global__ __launch_bounds__(1024) void scatter_kernel(
    const int* __restrict__ idx, const int* __restrict__ counts,
    int* __restrict__ cursors, int* __restrict__ perm)
{
    __shared__ int lcnt[KTYPES], lbase[KTYPES];
    int t = threadIdx.x;
    if (t < KTYPES) lcnt[t] = 0;
    __syncthreads();
    int n = blockIdx.x * 1024 + t;         // 128 blocks x 1024
    int k = idx[n];
    int lpos = atomicAdd(&lcnt[k], 1);
    __syncthreads();
    if (t < KTYPES)
        lbase[t] = (lcnt[t] > 0) ? atomicAdd(&cursors[t], lcnt[t]) : 0;
    __syncthreads();
    int gof = 0, off = 0;
    #pragma unroll
    for (int j = 0; j < KTYPES; ++j) {
        int cj = counts[j];
        if (j == k) gof = off;
        off += cj;
    }
    perm[gof + lbase[k] + lpos] = n;
}

// Pass C: main. Block = 64 samples (4 waves x 16). No LDS, no barriers.
// MFMA 16x16x32 computes T^T = (W_k^T)(U^T):
//   A[i][kk]: i = e_local = lane&15, kk = (lane>>4)*8+j  -> Wt[eb*16+lm][dc*32+lq*8+j]
//   B[kk][n]: n = sample  = lane&15, kk = (lane>>4)*8+j  -> U[s_lm][dc*32+lq*8+j]
//   D[i][j] : i = lq*4+r (e), j = lm (sample)
// => lane folds acc with exact fp32 float4 of V[s_lm][eb*16+lq*4 .. +4).
__global__ __launch_bounds__(256, 4) void bilinear_main(
    const float* __restrict__ U, const float* __restrict__ V,
    const _Float16* __restrict__ Wt, const int* __restrict__ perm,
    const int* __restrict__ counts, float* __restrict__ out)
{
    // derive (k, base, gof, cnt) from counts[8]
    int tblk = blockIdx.x;
    int k = -1, base = 0, gof = 0, cnt = 0;
    {
        int toff = 0, off = 0;
        #pragma unroll
        for (int j = 0; j < KTYPES; ++j) {
            int cj = counts[j];
            int nt = (cj + TILE_M - 1) >> 6;
            if (tblk >= toff && tblk < toff + nt) {
                k = j; base = (tblk - toff) * TILE_M; gof = off; cnt = cj;
            }
            toff += nt; off += cj;
        }
    }
    if (k < 0) return;

    int tid = threadIdx.x;
    int wave = tid >> 6, lane = tid & 63;
    int lq = lane >> 4, lm = lane & 15;

    int row_local = base + wave * 16 + lm;
    bool valid = row_local < cnt;
    int rl = valid ? row_local : (cnt - 1);
    int sm = perm[gof + rl];

    const float* Urow = U + ((size_t)sm << 8);
    const float* Vrow = V + ((size_t)sm << 8);
    const _Float16* Wk = Wt + ((size_t)k << 16);

    // U fragments (B operand), loaded once: d = dc*32 + lq*8 + 0..7
    f16x8 ufrag[8];
    #pragma unroll
    for (int dc = 0; dc < 8; ++dc) {
        float4 f0 = *(const float4*)(Urow + dc * 32 + lq * 8);
        float4 f1 = *(const float4*)(Urow + dc * 32 + lq * 8 + 4);
        f16x8 a;
        a[0] = (_Float16)f0.x; a[1] = (_Float16)f0.y;
        a[2] = (_Float16)f0.z; a[3] = (_Float16)f0.w;
        a[4] = (_Float16)f1.x; a[5] = (_Float16)f1.y;
        a[6] = (_Float16)f1.z; a[7] = (_Float16)f1.w;
        ufrag[dc] = a;
    }

    // V pipeline: 2-deep manual rotation (static names -> registers, no scratch)
    float4 vcur = *(const float4*)(Vrow + 0 * 16 + lq * 4);
    float4 vnxt = *(const float4*)(Vrow + 1 * 16 + lq * 4);
    float spart = 0.f;

    #pragma unroll 2
    for (int eb = 0; eb < 16; ++eb) {
        const _Float16* ap = Wk + ((size_t)(eb * 16 + lm) << 8) + lq * 8;
        f32x4 acc = {0.f, 0.f, 0.f, 0.f};
        #pragma unroll
        for (int dc = 0; dc < 8; ++dc) {
            f16x8 a = *(const f16x8*)(ap + dc * 32);
            acc = __builtin_amdgcn_mfma_f32_16x16x32_f16(a, ufrag[dc], acc, 0, 0, 0);
        }
        float4 vuse = vcur;
        vcur = vnxt;
        int ebn = (eb + 2 < 16) ? (eb + 2) : 0;      // clamped prefetch (value unused at tail)
        vnxt = *(const float4*)(Vrow + ebn * 16 + lq * 4);
        spart += acc[0] * vuse.x + acc[1] * vuse.y + acc[2] * vuse.z + acc[3] * vuse.w;
    }

    // reduce across lq (lane bits 4,5)
    spart += __shfl_xor(spart, 16);
    spart += __shfl_xor(spart, 32);

    if (lq == 0 && valid)
        out[sm] = 1.0f / (1.0f + __expf(-spart));
}

extern "C" void kernel_launch(void* const* d_in, const int* in_sizes, int n_in,
                              void* d_out, int out_size, void* d_ws, size_t ws_size,
                              hipStream_t stream) {
    const float* U = (const float*)d_in[0];
    const float* V = (const float*)d_in[1];
    const float* W = (const float*)d_in[2];
    const int* idx = (const int*)d_in[3];
    float* out = (float*)d_out;
    char* ws = (char*)d_ws;

    _Float16* Wt = (_Float16*)(ws + WT_OFF);
    int* counts  = (int*)(ws + CNT_OFF);
    int* cursors = (int*)(ws + CUR_OFF);
    int* perm    = (int*)(ws + PERM_OFF);

    hipMemsetAsync(ws + CNT_OFF, 0, 64, stream);            // counts + cursors
    prep_kernel<<<128, 256, 0, stream>>>(W, Wt, idx, counts);
    scatter_kernel<<<128, 1024, 0, stream>>>(idx, counts, cursors, perm);
    bilinear_main<<<MAXTILES, 256, 0, stream>>>(U, V, Wt, perm, counts, out);
}